// Round 12
// baseline (231.596 us; speedup 1.0000x reference)
//
#include <hip/hip_runtime.h>
#include <math.h>

#define HH 128
#define WW 128
#define CCH 256
#define NHH 8
#define NPP 4
#define DDIM 32
#define HWW (HH * WW)
#define BB 2
#define MM (BB * HWW)
#define KK 256

typedef __attribute__((ext_vector_type(8))) __bf16 bf16x8;
typedef __attribute__((ext_vector_type(8))) short s16x8;
typedef __attribute__((ext_vector_type(4))) short s16x4;
typedef __attribute__((ext_vector_type(4))) float f32x4;

// log2(10000)/64
#define PE_LOG2_STEP 0.20762050593f

__device__ __forceinline__ float pe_val(int c, int y, int x) {
    int j = (c & 127) >> 1;
    float pos = (c < 128) ? (float)y : (float)x;
    float f = exp2f(-(float)j * PE_LOG2_STEP);   // single v_exp_f32
    float s, cs;
    __sincosf(pos * f, &s, &cs);
    return (c & 1) ? cs : s;
}

__device__ __forceinline__ short f2b(float f) {
    union { float f; unsigned u; } c; c.f = f;
    unsigned r = c.u + 0x7FFF + ((c.u >> 16) & 1);
    return (short)(r >> 16);
}

__device__ __forceinline__ float b2f(short s) {
    union { unsigned u; float f; } c;
    c.u = ((unsigned)(unsigned short)s) << 16;
    return c.f;
}

// async global->LDS, 16B per lane; LDS dest is wave-uniform base + lane*16
__device__ __forceinline__ void gload16(const short* g, short* l) {
    __builtin_amdgcn_global_load_lds(
        (const __attribute__((address_space(1))) unsigned int*)g,
        (__attribute__((address_space(3))) unsigned int*)l, 16, 0, 0);
}

// ---------- scaled output-PE table (bf16) ----------
__global__ __launch_bounds__(256) void pe_table_kernel(
    const float* __restrict__ out_scale, short* __restrict__ pe_b)
{
    int t = blockIdx.x * 256 + threadIdx.x;   // pair index: HWW*128 total
    int cp = t & 127;
    int p = t >> 7;
    int y = p >> 7, x = p & 127;
    int c2 = cp * 2;
    int j = (c2 & 127) >> 1;
    float pos = (c2 < 128) ? (float)y : (float)x;
    float f = exp2f(-(float)j * PE_LOG2_STEP);
    float s, c;
    __sincosf(pos * f, &s, &c);
    float sc = out_scale[0];
    pe_b[(size_t)p * CCH + c2] = f2b(sc * s);
    pe_b[(size_t)p * CCH + c2 + 1] = f2b(sc * c);
}

// ---------- convert big weights (K=256,N=256 row-major) -> W^T bf16 [N][K] ----------
__global__ __launch_bounds__(256) void convert_big_w(
    const float* __restrict__ conv_w, const float* __restrict__ vp_w,
    const float* __restrict__ op_w, short* __restrict__ wt)
{
    __shared__ float tile[32][33];
    int z = blockIdx.z;               // 0: conv, 1-4: vp, 5-8: op
    const float* src = (z == 0) ? conv_w
                     : (z <= 4) ? vp_w + (size_t)(z - 1) * KK * CCH
                                : op_w + (size_t)(z - 5) * KK * CCH;
    short* dst = wt + (size_t)z * KK * CCH;
    int k0 = blockIdx.x * 32, n0 = blockIdx.y * 32;
    int tx = threadIdx.x, ty = threadIdx.y;
    #pragma unroll
    for (int i = 0; i < 4; ++i)
        tile[ty + i * 8][tx] = src[(size_t)(k0 + ty + i * 8) * CCH + n0 + tx];
    __syncthreads();
    int t = ty * 32 + tx;
    int n_l = t >> 3, ks = (t & 7) * 4;
    s16x4 o;
    #pragma unroll
    for (int j = 0; j < 4; ++j) o[j] = f2b(tile[ks + j][n_l]);
    *(s16x4*)&dst[(size_t)(n0 + n_l) * KK + k0 + ks] = o;
}

// ---------- convert + concat skinny weights -> wt[L][96][256], bias_cat[L][96] ----------
__global__ __launch_bounds__(256) void convert_offaw_w(
    const float* __restrict__ off_w, const float* __restrict__ aw_w,
    const float* __restrict__ off_b, const float* __restrict__ aw_b,
    short* __restrict__ wt, float* __restrict__ bias_cat)
{
    __shared__ float tile[32][33];
    int l = blockIdx.z;
    int nt = blockIdx.y;              // 0,1: off cols nt*32 ; 2: aw cols 0..31
    int k0 = blockIdx.x * 32;
    const float* src; int N, ncol0;
    if (nt < 2) { src = off_w + (size_t)l * KK * 64; N = 64; ncol0 = nt * 32; }
    else        { src = aw_w + (size_t)l * KK * 32; N = 32; ncol0 = 0; }
    int tx = threadIdx.x, ty = threadIdx.y;
    #pragma unroll
    for (int i = 0; i < 4; ++i)
        tile[ty + i * 8][tx] = src[(size_t)(k0 + ty + i * 8) * N + ncol0 + tx];
    __syncthreads();
    int t = ty * 32 + tx;
    int n_l = t >> 3, ks = (t & 7) * 4;
    s16x4 o;
    #pragma unroll
    for (int j = 0; j < 4; ++j) o[j] = f2b(tile[ks + j][n_l]);
    *(s16x4*)&wt[((size_t)l * 96 + nt * 32 + n_l) * KK + k0 + ks] = o;
    if (blockIdx.x == 0 && t < 32) {
        int col = nt * 32 + t;
        bias_cat[l * 96 + col] = (nt < 2) ? off_b[l * 64 + ncol0 + t]
                                          : aw_b[l * 32 + t];
    }
}

// ---------- transpose (B,C,HW) -> kt bf16 (B,HW,C) with input PE ----------
__global__ __launch_bounds__(256) void transpose_pe_kernel(
    const float* __restrict__ ego, const float* __restrict__ in_scale,
    short* __restrict__ ktb)
{
    __shared__ float tile[32][33];    // [c_local][p_local]
    int b = blockIdx.z;
    int c0 = blockIdx.x * 32;
    int p0 = blockIdx.y * 32;
    int tx = threadIdx.x, ty = threadIdx.y; // (32,8)
    const float* egob = ego + (size_t)b * CCH * HWW;
    #pragma unroll
    for (int i = 0; i < 4; ++i)
        tile[ty + i * 8][tx] = egob[(size_t)(c0 + ty + i * 8) * HWW + p0 + tx];
    __syncthreads();
    float isc = in_scale[0];
    int t = ty * 32 + tx;
    int p_l = t >> 3, cs = (t & 7) * 4;
    int p = p0 + p_l;
    int y = p >> 7, x = p & 127;
    s16x4 o;
    #pragma unroll
    for (int j = 0; j < 4; ++j) {
        int c = c0 + cs + j;
        o[j] = f2b(tile[cs + j][p_l] + isc * pe_val(c, y, x));
    }
    *(s16x4*)&ktb[((size_t)b * HWW + p) * CCH + c0 + cs] = o;
}

// ---------- stage a full 64-row x K=256 A-slab into LDS (32 KiB), swizzled ----------
__device__ __forceinline__ void stage_slab64(
    const short* __restrict__ src, short* As, int m0, int w, int lane)
{
    #pragma unroll
    for (int i = 0; i < 8; ++i) {
        int c = w * 64 + i * 256;        // wave-uniform chunk base
        int cc = c + lane;               // this lane's chunk (0..2047)
        int r = cc >> 5, col = cc & 31, ks = col >> 3, u = col & 7;
        gload16(src + (size_t)(m0 + r) * KK + ks * 64 + ((u ^ (r & 7)) << 3),
                As + c * 8);
    }
}

// ================= GEMM core B: gload_lds double-buffered (R5 proven) ==============
template<int NINST>
__device__ __forceinline__ void stage_tile(
    const short* __restrict__ src, short* dst, int row0, int ks, int w, int lane)
{
    #pragma unroll
    for (int i = 0; i < NINST; ++i) {
        int c = w * 64 + i * 256;        // wave-uniform chunk base
        int cc = c + lane;               // this lane's chunk
        int r = cc >> 3, u = cc & 7;
        gload16(src + (size_t)(row0 + r) * KK + ks * 64 + ((u ^ (r & 7)) << 3),
                dst + c * 8);
    }
}

template<int BM, int BN, int WM, int WN>
__device__ __forceinline__ void gemm_core_db(
    const short* __restrict__ A, const short* __restrict__ Bt,
    short* AsBase, short* BsBase, int m0, int n0, int tid,
    f32x4 (&acc)[WM / 16][WN / 16])
{
    constexpr int MF = WM / 16, NF = WN / 16;
    constexpr int WAVES_N = BN / WN;
    constexpr int A_INST = (BM * 8) / 256;
    constexpr int B_INST = (BN * 8) / 256;
    int w = tid >> 6, lane = tid & 63;
    int g = lane >> 4, l16 = lane & 15;
    int wr = w / WAVES_N, wc = w % WAVES_N;
    short* As0 = AsBase; short* As1 = AsBase + BM * 64;
    short* Bs0 = BsBase; short* Bs1 = BsBase + BN * 64;

    stage_tile<A_INST>(A, As0, m0, 0, w, lane);
    stage_tile<B_INST>(Bt, Bs0, n0, 0, w, lane);
    asm volatile("s_waitcnt vmcnt(0)" ::: "memory");
    __syncthreads();

    #pragma unroll
    for (int ks = 0; ks < 4; ++ks) {
        short* Ac = (ks & 1) ? As1 : As0;
        short* Bc = (ks & 1) ? Bs1 : Bs0;
        short* An = (ks & 1) ? As0 : As1;
        short* Bn = (ks & 1) ? Bs0 : Bs1;
        if (ks < 3) {
            stage_tile<A_INST>(A, An, m0, ks + 1, w, lane);
            stage_tile<B_INST>(Bt, Bn, n0, ks + 1, w, lane);
        }
        #pragma unroll
        for (int kh = 0; kh < 2; ++kh) {
            bf16x8 af[MF], bfr[NF];
            #pragma unroll
            for (int mf = 0; mf < MF; ++mf) {
                int r = wr * WM + mf * 16 + l16, s = kh * 4 + g;
                af[mf] = *(const bf16x8*)(Ac + r * 64 + ((s ^ (r & 7)) * 8));
            }
            #pragma unroll
            for (int nf = 0; nf < NF; ++nf) {
                int r = wc * WN + nf * 16 + l16, s = kh * 4 + g;
                bfr[nf] = *(const bf16x8*)(Bc + r * 64 + ((s ^ (r & 7)) * 8));
            }
            #pragma unroll
            for (int mf = 0; mf < MF; ++mf)
                #pragma unroll
                for (int nf = 0; nf < NF; ++nf)
                    acc[mf][nf] = __builtin_amdgcn_mfma_f32_16x16x32_bf16(
                        af[mf], bfr[nf], acc[mf][nf], 0, 0, 0);
        }
        if (ks < 3) {
            __builtin_amdgcn_sched_barrier(0);
            asm volatile("s_waitcnt vmcnt(0)" ::: "memory");
            __syncthreads();
        }
    }
}

// ---------- conv+v: A-slab persistent in LDS, z-loop in-block (R10 proven) ----------
__global__ __launch_bounds__(256) void gemm_conv_v(
    const short* __restrict__ ktb, const short* __restrict__ wt_big,
    const float* __restrict__ conv_b, const float* __restrict__ vp_b,
    const short* __restrict__ pe_b, short* __restrict__ qb,
    short* __restrict__ vb16)
{
    __shared__ short As[64 * 256];   // full-K A slab (32 KiB)
    __shared__ short Bs[128 * 64];   // one k-step B tile (16 KiB)
    int tid = threadIdx.x;
    int w = tid >> 6, lane = tid & 63;
    int g = lane >> 4, l16 = lane & 15;
    int wr = w >> 1, wc = w & 1;
    int flat = blockIdx.x;
    int xcd = flat & 7;
    int idx = flat >> 3;            // 0..127 per XCD
    int mloc = idx & 63;            // 64 m-tiles per XCD chunk
    int n0 = (idx >> 6) * 128;
    int m0 = (xcd * 64 + mloc) * 64;

    stage_slab64(ktb, As, m0, w, lane);
    // prefetch z=0, ks=0 B tile into regs (overlaps slab DMA)
    s16x8 rb[4];
    #pragma unroll
    for (int i = 0; i < 4; ++i) {
        int task = tid + i * 256; int r = task >> 3, s = task & 7;
        rb[i] = *(const s16x8*)(wt_big + (size_t)(n0 + r) * KK + s * 8);
    }
    asm volatile("s_waitcnt vmcnt(0)" ::: "memory");
    __syncthreads();

    for (int z = 0; z < 5; ++z) {
        f32x4 acc[2][4] = {};
        for (int ks = 0; ks < 4; ++ks) {
            __syncthreads();   // previous compute done reading Bs
            #pragma unroll
            for (int i = 0; i < 4; ++i) {
                int task = tid + i * 256; int r = task >> 3, s = task & 7;
                *(s16x8*)&Bs[r * 64 + ((s ^ (r & 7)) * 8)] = rb[i];
            }
            __syncthreads();
            // prefetch next B k-step (possibly next z's first)
            if (ks < 3) {
                const short* Bz = wt_big + (size_t)z * KK * CCH;
                #pragma unroll
                for (int i = 0; i < 4; ++i) {
                    int task = tid + i * 256; int r = task >> 3, s = task & 7;
                    rb[i] = *(const s16x8*)(Bz + (size_t)(n0 + r) * KK + (ks + 1) * 64 + s * 8);
                }
            } else if (z < 4) {
                const short* Bz = wt_big + (size_t)(z + 1) * KK * CCH;
                #pragma unroll
                for (int i = 0; i < 4; ++i) {
                    int task = tid + i * 256; int r = task >> 3, s = task & 7;
                    rb[i] = *(const s16x8*)(Bz + (size_t)(n0 + r) * KK + s * 8);
                }
            }
            #pragma unroll
            for (int kh = 0; kh < 2; ++kh) {
                int s = kh * 4 + g;
                bf16x8 af[2], bfr[4];
                #pragma unroll
                for (int mf = 0; mf < 2; ++mf) {
                    int r = wr * 32 + mf * 16 + l16;
                    af[mf] = *(const bf16x8*)(As + r * 256 + (ks * 8 + (s ^ (r & 7))) * 8);
                }
                #pragma unroll
                for (int nf = 0; nf < 4; ++nf) {
                    int r = wc * 64 + nf * 16 + l16;
                    bfr[nf] = *(const bf16x8*)(Bs + r * 64 + ((s ^ (r & 7)) * 8));
                }
                #pragma unroll
                for (int mf = 0; mf < 2; ++mf)
                    #pragma unroll
                    for (int nf = 0; nf < 4; ++nf)
                        acc[mf][nf] = __builtin_amdgcn_mfma_f32_16x16x32_bf16(
                            af[mf], bfr[nf], acc[mf][nf], 0, 0, 0);
            }
        }
        // epilogue for this z
        const float* bias = (z == 0) ? conv_b : vp_b + (size_t)(z - 1) * CCH;
        short* vz = vb16 + (size_t)(z - 1) * MM * CCH;
        #pragma unroll
        for (int mf = 0; mf < 2; ++mf) {
            #pragma unroll
            for (int nf = 0; nf < 4; ++nf) {
                int col = n0 + wc * 64 + nf * 16 + l16;
                float bv = bias[col];
                #pragma unroll
                for (int j = 0; j < 4; ++j) {
                    int row = m0 + wr * 32 + mf * 16 + g * 4 + j;
                    float vv = acc[mf][nf][j] + bv;
                    if (z == 0) {
                        int p = row & (HWW - 1);
                        qb[(size_t)row * CCH + col] =
                            f2b(vv + b2f(pe_b[(size_t)p * CCH + col]));
                    } else {
                        int b = row >> 14, p = row & (HWW - 1);
                        int h = col >> 5, d = col & 31;
                        vz[(((size_t)(b * NHH + h)) * HWW + p) * DDIM + d] = f2b(vv);
                    }
                }
            }
        }
    }
}

// ---------- scores = q @ [off|aw] + bias  (N = 96, f32 out), BM=64 dbuf ----------
__global__ __launch_bounds__(256) void gemm_scores(
    const short* __restrict__ qb, const short* __restrict__ wt,
    const float* __restrict__ bias, float* __restrict__ scores)
{
    __shared__ short As[2 * 64 * 64];
    __shared__ short Bs[2 * 96 * 64];
    int tid = threadIdx.x;
    int m0 = blockIdx.y * 64;
    f32x4 acc[2][3] = {};
    gemm_core_db<64, 96, 32, 48>(qb, wt, As, Bs, m0, 0, tid, acc);

    int w = tid >> 6, lane = tid & 63;
    int g = lane >> 4, l16 = lane & 15;
    int wr = w >> 1, wc = w & 1;
    #pragma unroll
    for (int mf = 0; mf < 2; ++mf) {
        #pragma unroll
        for (int nf = 0; nf < 3; ++nf) {
            int col = wc * 48 + nf * 16 + l16;
            float bv = bias[col];
            #pragma unroll
            for (int j = 0; j < 4; ++j) {
                int row = m0 + wr * 32 + mf * 16 + g * 4 + j;
                scores[(size_t)row * 96 + col] = acc[mf][nf][j] + bv;
            }
        }
    }
}

// ---------- out = attn @ op_w + op_b + q(bf16), XCD-chunked flat grid (512) ----------
template<bool FINAL>
__global__ __launch_bounds__(256) void gemm_op(
    const short* __restrict__ attnb, const short* __restrict__ wt,
    const float* __restrict__ bias, const short* __restrict__ pe_b,
    float* __restrict__ outf, short* __restrict__ qb)
{
    __shared__ short As[2 * 128 * 64];
    __shared__ short Bs[2 * 128 * 64];
    int tid = threadIdx.x;
    int flat = blockIdx.x;
    int xcd = flat & 7;
    int idx = flat >> 3;            // 0..63 per XCD
    int mloc = idx & 31;
    int n0 = (idx >> 5) * 128;
    int m0 = (xcd * 32 + mloc) * 128;
    f32x4 acc[4][4] = {};
    gemm_core_db<128, 128, 64, 64>(attnb, wt, As, Bs, m0, n0, tid, acc);

    int w = tid >> 6, lane = tid & 63;
    int g = lane >> 4, l16 = lane & 15;
    int wr = w >> 1, wc = w & 1;
    #pragma unroll
    for (int mf = 0; mf < 4; ++mf) {
        #pragma unroll
        for (int nf = 0; nf < 4; ++nf) {
            int col = n0 + wc * 64 + nf * 16 + l16;
            float bv = bias[col];
            #pragma unroll
            for (int j = 0; j < 4; ++j) {
                int row = m0 + wr * 64 + mf * 16 + g * 4 + j;
                float vv = acc[mf][nf][j] + bv + b2f(qb[(size_t)row * CCH + col]);
                if (FINAL) {
                    outf[(size_t)row * CCH + col] = vv;
                } else {
                    int p = row & (HWW - 1);
                    qb[(size_t)row * CCH + col] =
                        f2b(vv + b2f(pe_b[(size_t)p * CCH + col]));
                }
            }
        }
    }
}

// ---------- deformable sampling + inline softmax (8 lanes/head, 128B spans) ----------
// Lanes 0-3 of each 8-lane group take the xi0 column, lanes 4-7 take xi0+1:
// one 128B contiguous span per bilinear row -> half the L2 requests of 4-corner form.
// Out-of-range span reads have provably zero weight (validity conds imply it).
__device__ __forceinline__ void fma8(uint4 u, float w, float* a) {
    a[0] = fmaf(__uint_as_float(u.x << 16), w, a[0]);
    a[1] = fmaf(__uint_as_float(u.x & 0xffff0000u), w, a[1]);
    a[2] = fmaf(__uint_as_float(u.y << 16), w, a[2]);
    a[3] = fmaf(__uint_as_float(u.y & 0xffff0000u), w, a[3]);
    a[4] = fmaf(__uint_as_float(u.z << 16), w, a[4]);
    a[5] = fmaf(__uint_as_float(u.z & 0xffff0000u), w, a[5]);
    a[6] = fmaf(__uint_as_float(u.w << 16), w, a[6]);
    a[7] = fmaf(__uint_as_float(u.w & 0xffff0000u), w, a[7]);
}

__global__ __launch_bounds__(256) void deform_kernel(
    const short* __restrict__ vb16, const float* __restrict__ scores,
    short* __restrict__ attnb)
{
    int tid = threadIdx.x;
    int gi = tid >> 3;              // 0..31: (p,h) group in block
    int lane8 = tid & 7;
    int xside = lane8 >> 2;         // 0: xi0 column, 1: xi0+1 column
    int dl = (lane8 & 3) * 8;       // 8 channels per lane
    long gid = (long)blockIdx.x * 32 + gi; // (b*HW+p)*NH + h
    int h = (int)(gid & 7);
    long bp = gid >> 3;
    int p = (int)(bp & (HWW - 1));
    int b = (int)(bp >> 14);
    int y = p >> 7, x = p & 127;
    const float* srow = scores + bp * 96;
    float4 sc4 = *(const float4*)(srow + 64 + h * 4);
    float mx = fmaxf(fmaxf(sc4.x, sc4.y), fmaxf(sc4.z, sc4.w));
    float e0 = __expf(sc4.x - mx), e1 = __expf(sc4.y - mx);
    float e2 = __expf(sc4.z - mx), e3 = __expf(sc4.w - mx);
    float inv = 1.f / (e0 + e1 + e2 + e3);
    float wa4[4] = {e0 * inv, e1 * inv, e2 * inv, e3 * inv};
    float4 o01 = *(const float4*)(srow + h * 8);
    float4 o23 = *(const float4*)(srow + h * 8 + 4);
    float oxs[4] = {o01.x, o01.z, o23.x, o23.z};
    float oys[4] = {o01.y, o01.w, o23.y, o23.w};
    const short* vbase = vb16 + (size_t)(b * NHH + h) * HWW * DDIM;
    float a[8] = {};
    #pragma unroll
    for (int pt = 0; pt < NPP; ++pt) {
        float wa = wa4[pt];
        float ix = (float)x + oxs[pt];     // grid_sample chain collapses to x+ox
        float iy = (float)y + oys[pt];
        float x0f = floorf(ix), y0f = floorf(iy);
        float fx = ix - x0f, fy = iy - y0f;
        float wx0v = (x0f >= 0.f && x0f <= 127.f) ? (1.f - fx) : 0.f;
        float wx1v = (x0f >= -1.f && x0f <= 126.f) ? fx : 0.f;
        float wxl = xside ? wx1v : wx0v;
        float wy0 = ((y0f >= 0.f && y0f <= 127.f) ? (1.f - fy) : 0.f) * wa;
        float wy1 = ((y0f >= -1.f && y0f <= 126.f) ? fy : 0.f) * wa;
        int xs = (int)fminf(fmaxf(x0f, -1.f), 127.f);   // span start (may be -1)
        int yi0 = (int)fminf(fmaxf(y0f, 0.f), 127.f);
        int yi1 = (int)fminf(fmaxf(y0f + 1.f, 0.f), 127.f);
        long off0 = (long)(yi0 * WW + xs) * DDIM + xside * DDIM + dl;
        long off1 = (long)(yi1 * WW + xs) * DDIM + xside * DDIM + dl;
        uint4 u0 = *(const uint4*)(vbase + off0);
        uint4 u1 = *(const uint4*)(vbase + off1);
        fma8(u0, wxl * wy0, a);
        fma8(u1, wxl * wy1, a);
    }
    // combine the two corner columns: lane L <- L + (L^4)
    #pragma unroll
    for (int j = 0; j < 8; ++j) a[j] += __shfl_xor(a[j], 4);
    if (xside == 0) {
        s16x8 o;
        #pragma unroll
        for (int j = 0; j < 8; ++j) o[j] = f2b(a[j]);
        *(s16x8*)&attnb[bp * CCH + h * DDIM + dl] = o;
    }
}

extern "C" void kernel_launch(void* const* d_in, const int* in_sizes, int n_in,
                              void* d_out, int out_size, void* d_ws, size_t ws_size,
                              hipStream_t stream) {
    const float* ego       = (const float*)d_in[0];
    const float* conv_w    = (const float*)d_in[1];
    const float* conv_b    = (const float*)d_in[2];
    const float* in_scale  = (const float*)d_in[3];
    const float* out_scale = (const float*)d_in[4];
    const float* off_w     = (const float*)d_in[5];
    const float* off_b     = (const float*)d_in[6];
    const float* aw_w      = (const float*)d_in[7];
    const float* aw_b      = (const float*)d_in[8];
    const float* vp_w      = (const float*)d_in[9];
    const float* vp_b      = (const float*)d_in[10];
    const float* op_w      = (const float*)d_in[11];
    const float* op_b      = (const float*)d_in[12];
    float* out = (float*)d_out;

    float* scores   = (float*)d_ws;                    // MM*96 f32
    float* bias_cat = scores + (size_t)MM * 96;        // 4*96
    short* pe_b     = (short*)(bias_cat + 4 * 96);     // HWW*256 bf16
    short* ktb      = pe_b + (size_t)HWW * CCH;        // MM*256 bf16
    short* qb       = ktb + (size_t)MM * CCH;          // MM*256 bf16 (q + residual)
    short* vb16     = qb + (size_t)MM * CCH;           // 4 * MM*256 bf16 (head-major)
    short* attnb    = vb16 + (size_t)4 * MM * CCH;
    short* wt_big   = attnb + (size_t)MM * CCH;        // 9*256*256 bf16
    short* wt_offaw = wt_big + (size_t)9 * KK * CCH;   // 4*96*256 bf16

    pe_table_kernel<<<HWW * 128 / 256, 256, 0, stream>>>(out_scale, pe_b);
    convert_big_w<<<dim3(8, 8, 9), dim3(32, 8), 0, stream>>>(conv_w, vp_w, op_w, wt_big);
    convert_offaw_w<<<dim3(8, 3, 4), dim3(32, 8), 0, stream>>>(
        off_w, aw_w, off_b, aw_b, wt_offaw, bias_cat);
    transpose_pe_kernel<<<dim3(8, 512, 2), dim3(32, 8), 0, stream>>>(ego, in_scale, ktb);

    // A-slab persistent + in-block z loop; XCD-chunked m so slab is L2-resident
    gemm_conv_v<<<1024, 256, 0, stream>>>(
        ktb, wt_big, conv_b, vp_b, pe_b, qb, vb16);

    for (int l = 0; l < 4; ++l) {
        gemm_scores<<<dim3(1, 512), 256, 0, stream>>>(
            qb, wt_offaw + (size_t)l * 96 * KK, bias_cat + l * 96, scores);
        deform_kernel<<<MM * NHH / 32, 256, 0, stream>>>(
            vb16 + (size_t)l * MM * CCH, scores, attnb);
        if (l < 3) {
            gemm_op<false><<<512, 256, 0, stream>>>(
                attnb, wt_big + (size_t)(5 + l) * KK * CCH, op_b + l * CCH,
                pe_b, nullptr, qb);
        } else {
            gemm_op<true><<<512, 256, 0, stream>>>(
                attnb, wt_big + (size_t)(5 + l) * KK * CCH, op_b + l * CCH,
                pe_b, out, qb);
        }
    }
}

// Round 13
// 213.676 us; speedup vs baseline: 1.0839x; 1.0839x over previous
//
#include <hip/hip_runtime.h>
#include <math.h>

#define HH 128
#define WW 128
#define CCH 256
#define NHH 8
#define NPP 4
#define DDIM 32
#define HWW (HH * WW)
#define BB 2
#define MM (BB * HWW)
#define KK 256

typedef __attribute__((ext_vector_type(8))) __bf16 bf16x8;
typedef __attribute__((ext_vector_type(8))) short s16x8;
typedef __attribute__((ext_vector_type(4))) short s16x4;
typedef __attribute__((ext_vector_type(4))) float f32x4;

// log2(10000)/64
#define PE_LOG2_STEP 0.20762050593f

__device__ __forceinline__ float pe_val(int c, int y, int x) {
    int j = (c & 127) >> 1;
    float pos = (c < 128) ? (float)y : (float)x;
    float f = exp2f(-(float)j * PE_LOG2_STEP);   // single v_exp_f32
    float s, cs;
    __sincosf(pos * f, &s, &cs);
    return (c & 1) ? cs : s;
}

__device__ __forceinline__ short f2b(float f) {
    union { float f; unsigned u; } c; c.f = f;
    unsigned r = c.u + 0x7FFF + ((c.u >> 16) & 1);
    return (short)(r >> 16);
}

__device__ __forceinline__ float b2f(short s) {
    union { unsigned u; float f; } c;
    c.u = ((unsigned)(unsigned short)s) << 16;
    return c.f;
}

// async global->LDS, 16B per lane; LDS dest is wave-uniform base + lane*16
__device__ __forceinline__ void gload16(const short* g, short* l) {
    __builtin_amdgcn_global_load_lds(
        (const __attribute__((address_space(1))) unsigned int*)g,
        (__attribute__((address_space(3))) unsigned int*)l, 16, 0, 0);
}

// ---------- scaled output-PE table (bf16) ----------
__global__ __launch_bounds__(256) void pe_table_kernel(
    const float* __restrict__ out_scale, short* __restrict__ pe_b)
{
    int t = blockIdx.x * 256 + threadIdx.x;   // pair index: HWW*128 total
    int cp = t & 127;
    int p = t >> 7;
    int y = p >> 7, x = p & 127;
    int c2 = cp * 2;
    int j = (c2 & 127) >> 1;
    float pos = (c2 < 128) ? (float)y : (float)x;
    float f = exp2f(-(float)j * PE_LOG2_STEP);
    float s, c;
    __sincosf(pos * f, &s, &c);
    float sc = out_scale[0];
    pe_b[(size_t)p * CCH + c2] = f2b(sc * s);
    pe_b[(size_t)p * CCH + c2 + 1] = f2b(sc * c);
}

// ---------- convert big weights (K=256,N=256 row-major) -> W^T bf16 [N][K] ----------
__global__ __launch_bounds__(256) void convert_big_w(
    const float* __restrict__ conv_w, const float* __restrict__ vp_w,
    const float* __restrict__ op_w, short* __restrict__ wt)
{
    __shared__ float tile[32][33];
    int z = blockIdx.z;               // 0: conv, 1-4: vp, 5-8: op
    const float* src = (z == 0) ? conv_w
                     : (z <= 4) ? vp_w + (size_t)(z - 1) * KK * CCH
                                : op_w + (size_t)(z - 5) * KK * CCH;
    short* dst = wt + (size_t)z * KK * CCH;
    int k0 = blockIdx.x * 32, n0 = blockIdx.y * 32;
    int tx = threadIdx.x, ty = threadIdx.y;
    #pragma unroll
    for (int i = 0; i < 4; ++i)
        tile[ty + i * 8][tx] = src[(size_t)(k0 + ty + i * 8) * CCH + n0 + tx];
    __syncthreads();
    int t = ty * 32 + tx;
    int n_l = t >> 3, ks = (t & 7) * 4;
    s16x4 o;
    #pragma unroll
    for (int j = 0; j < 4; ++j) o[j] = f2b(tile[ks + j][n_l]);
    *(s16x4*)&dst[(size_t)(n0 + n_l) * KK + k0 + ks] = o;
}

// ---------- convert + concat skinny weights -> wt[L][96][256], bias_cat[L][96] ----------
__global__ __launch_bounds__(256) void convert_offaw_w(
    const float* __restrict__ off_w, const float* __restrict__ aw_w,
    const float* __restrict__ off_b, const float* __restrict__ aw_b,
    short* __restrict__ wt, float* __restrict__ bias_cat)
{
    __shared__ float tile[32][33];
    int l = blockIdx.z;
    int nt = blockIdx.y;              // 0,1: off cols nt*32 ; 2: aw cols 0..31
    int k0 = blockIdx.x * 32;
    const float* src; int N, ncol0;
    if (nt < 2) { src = off_w + (size_t)l * KK * 64; N = 64; ncol0 = nt * 32; }
    else        { src = aw_w + (size_t)l * KK * 32; N = 32; ncol0 = 0; }
    int tx = threadIdx.x, ty = threadIdx.y;
    #pragma unroll
    for (int i = 0; i < 4; ++i)
        tile[ty + i * 8][tx] = src[(size_t)(k0 + ty + i * 8) * N + ncol0 + tx];
    __syncthreads();
    int t = ty * 32 + tx;
    int n_l = t >> 3, ks = (t & 7) * 4;
    s16x4 o;
    #pragma unroll
    for (int j = 0; j < 4; ++j) o[j] = f2b(tile[ks + j][n_l]);
    *(s16x4*)&wt[((size_t)l * 96 + nt * 32 + n_l) * KK + k0 + ks] = o;
    if (blockIdx.x == 0 && t < 32) {
        int col = nt * 32 + t;
        bias_cat[l * 96 + col] = (nt < 2) ? off_b[l * 64 + ncol0 + t]
                                          : aw_b[l * 32 + t];
    }
}

// ---------- transpose (B,C,HW) -> kt bf16 (B,HW,C) with input PE ----------
__global__ __launch_bounds__(256) void transpose_pe_kernel(
    const float* __restrict__ ego, const float* __restrict__ in_scale,
    short* __restrict__ ktb)
{
    __shared__ float tile[32][33];    // [c_local][p_local]
    int b = blockIdx.z;
    int c0 = blockIdx.x * 32;
    int p0 = blockIdx.y * 32;
    int tx = threadIdx.x, ty = threadIdx.y; // (32,8)
    const float* egob = ego + (size_t)b * CCH * HWW;
    #pragma unroll
    for (int i = 0; i < 4; ++i)
        tile[ty + i * 8][tx] = egob[(size_t)(c0 + ty + i * 8) * HWW + p0 + tx];
    __syncthreads();
    float isc = in_scale[0];
    int t = ty * 32 + tx;
    int p_l = t >> 3, cs = (t & 7) * 4;
    int p = p0 + p_l;
    int y = p >> 7, x = p & 127;
    s16x4 o;
    #pragma unroll
    for (int j = 0; j < 4; ++j) {
        int c = c0 + cs + j;
        o[j] = f2b(tile[cs + j][p_l] + isc * pe_val(c, y, x));
    }
    *(s16x4*)&ktb[((size_t)b * HWW + p) * CCH + c0 + cs] = o;
}

// ---------- stage a full 64-row x K=256 A-slab into LDS (32 KiB), swizzled ----------
__device__ __forceinline__ void stage_slab64(
    const short* __restrict__ src, short* As, int m0, int w, int lane)
{
    #pragma unroll
    for (int i = 0; i < 8; ++i) {
        int c = w * 64 + i * 256;        // wave-uniform chunk base
        int cc = c + lane;               // this lane's chunk (0..2047)
        int r = cc >> 5, col = cc & 31, ks = col >> 3, u = col & 7;
        gload16(src + (size_t)(m0 + r) * KK + ks * 64 + ((u ^ (r & 7)) << 3),
                As + c * 8);
    }
}

// ================= GEMM core B: gload_lds double-buffered (R5 proven) ==============
template<int NINST>
__device__ __forceinline__ void stage_tile(
    const short* __restrict__ src, short* dst, int row0, int ks, int w, int lane)
{
    #pragma unroll
    for (int i = 0; i < NINST; ++i) {
        int c = w * 64 + i * 256;        // wave-uniform chunk base
        int cc = c + lane;               // this lane's chunk
        int r = cc >> 3, u = cc & 7;
        gload16(src + (size_t)(row0 + r) * KK + ks * 64 + ((u ^ (r & 7)) << 3),
                dst + c * 8);
    }
}

template<int BM, int BN, int WM, int WN>
__device__ __forceinline__ void gemm_core_db(
    const short* __restrict__ A, const short* __restrict__ Bt,
    short* AsBase, short* BsBase, int m0, int n0, int tid,
    f32x4 (&acc)[WM / 16][WN / 16])
{
    constexpr int MF = WM / 16, NF = WN / 16;
    constexpr int WAVES_N = BN / WN;
    constexpr int A_INST = (BM * 8) / 256;
    constexpr int B_INST = (BN * 8) / 256;
    int w = tid >> 6, lane = tid & 63;
    int g = lane >> 4, l16 = lane & 15;
    int wr = w / WAVES_N, wc = w % WAVES_N;
    short* As0 = AsBase; short* As1 = AsBase + BM * 64;
    short* Bs0 = BsBase; short* Bs1 = BsBase + BN * 64;

    stage_tile<A_INST>(A, As0, m0, 0, w, lane);
    stage_tile<B_INST>(Bt, Bs0, n0, 0, w, lane);
    asm volatile("s_waitcnt vmcnt(0)" ::: "memory");
    __syncthreads();

    #pragma unroll
    for (int ks = 0; ks < 4; ++ks) {
        short* Ac = (ks & 1) ? As1 : As0;
        short* Bc = (ks & 1) ? Bs1 : Bs0;
        short* An = (ks & 1) ? As0 : As1;
        short* Bn = (ks & 1) ? Bs0 : Bs1;
        if (ks < 3) {
            stage_tile<A_INST>(A, An, m0, ks + 1, w, lane);
            stage_tile<B_INST>(Bt, Bn, n0, ks + 1, w, lane);
        }
        #pragma unroll
        for (int kh = 0; kh < 2; ++kh) {
            bf16x8 af[MF], bfr[NF];
            #pragma unroll
            for (int mf = 0; mf < MF; ++mf) {
                int r = wr * WM + mf * 16 + l16, s = kh * 4 + g;
                af[mf] = *(const bf16x8*)(Ac + r * 64 + ((s ^ (r & 7)) * 8));
            }
            #pragma unroll
            for (int nf = 0; nf < NF; ++nf) {
                int r = wc * WN + nf * 16 + l16, s = kh * 4 + g;
                bfr[nf] = *(const bf16x8*)(Bc + r * 64 + ((s ^ (r & 7)) * 8));
            }
            #pragma unroll
            for (int mf = 0; mf < MF; ++mf)
                #pragma unroll
                for (int nf = 0; nf < NF; ++nf)
                    acc[mf][nf] = __builtin_amdgcn_mfma_f32_16x16x32_bf16(
                        af[mf], bfr[nf], acc[mf][nf], 0, 0, 0);
        }
        if (ks < 3) {
            __builtin_amdgcn_sched_barrier(0);
            asm volatile("s_waitcnt vmcnt(0)" ::: "memory");
            __syncthreads();
        }
    }
}

// ---------- conv+v: A-slab in LDS once, A-FRAGMENTS HOISTED TO REGS, z-loop ----------
// Per k-step LDS drops 16 -> 12 wave-instrs (A reads removed from the loop).
__global__ __launch_bounds__(256) void gemm_conv_v(
    const short* __restrict__ ktb, const short* __restrict__ wt_big,
    const float* __restrict__ conv_b, const float* __restrict__ vp_b,
    const short* __restrict__ pe_b, short* __restrict__ qb,
    short* __restrict__ vb16)
{
    __shared__ short As[64 * 256];   // full-K A slab (32 KiB)
    __shared__ short Bs[128 * 64];   // one k-step B tile (16 KiB)
    int tid = threadIdx.x;
    int w = tid >> 6, lane = tid & 63;
    int g = lane >> 4, l16 = lane & 15;
    int wr = w >> 1, wc = w & 1;
    int flat = blockIdx.x;
    int xcd = flat & 7;
    int idx = flat >> 3;            // 0..127 per XCD
    int mloc = idx & 63;            // 64 m-tiles per XCD chunk
    int n0 = (idx >> 6) * 128;
    int m0 = (xcd * 64 + mloc) * 64;

    stage_slab64(ktb, As, m0, w, lane);
    // prefetch z=0, ks=0 B tile into regs (overlaps slab DMA)
    s16x8 rb[4];
    #pragma unroll
    for (int i = 0; i < 4; ++i) {
        int task = tid + i * 256; int r = task >> 3, s = task & 7;
        rb[i] = *(const s16x8*)(wt_big + (size_t)(n0 + r) * KK + s * 8);
    }
    asm volatile("s_waitcnt vmcnt(0)" ::: "memory");
    __syncthreads();

    // hoist z-invariant A fragments into registers (16 x bf16x8 = 64 VGPR)
    bf16x8 afr[4][2][2];   // [ks][kh][mf] - all indices compile-time (full unroll)
    #pragma unroll
    for (int ks = 0; ks < 4; ++ks)
        #pragma unroll
        for (int kh = 0; kh < 2; ++kh)
            #pragma unroll
            for (int mf = 0; mf < 2; ++mf) {
                int s = kh * 4 + g;
                int r = wr * 32 + mf * 16 + l16;
                afr[ks][kh][mf] =
                    *(const bf16x8*)(As + r * 256 + (ks * 8 + (s ^ (r & 7))) * 8);
            }

    for (int z = 0; z < 5; ++z) {
        f32x4 acc[2][4] = {};
        #pragma unroll
        for (int ks = 0; ks < 4; ++ks) {
            __syncthreads();   // previous compute done reading Bs
            #pragma unroll
            for (int i = 0; i < 4; ++i) {
                int task = tid + i * 256; int r = task >> 3, s = task & 7;
                *(s16x8*)&Bs[r * 64 + ((s ^ (r & 7)) * 8)] = rb[i];
            }
            __syncthreads();
            // prefetch next B k-step (possibly next z's first)
            if (ks < 3) {
                const short* Bz = wt_big + (size_t)z * KK * CCH;
                #pragma unroll
                for (int i = 0; i < 4; ++i) {
                    int task = tid + i * 256; int r = task >> 3, s = task & 7;
                    rb[i] = *(const s16x8*)(Bz + (size_t)(n0 + r) * KK + (ks + 1) * 64 + s * 8);
                }
            } else if (z < 4) {
                const short* Bz = wt_big + (size_t)(z + 1) * KK * CCH;
                #pragma unroll
                for (int i = 0; i < 4; ++i) {
                    int task = tid + i * 256; int r = task >> 3, s = task & 7;
                    rb[i] = *(const s16x8*)(Bz + (size_t)(n0 + r) * KK + s * 8);
                }
            }
            #pragma unroll
            for (int kh = 0; kh < 2; ++kh) {
                int s = kh * 4 + g;
                bf16x8 bfr[4];
                #pragma unroll
                for (int nf = 0; nf < 4; ++nf) {
                    int r = wc * 64 + nf * 16 + l16;
                    bfr[nf] = *(const bf16x8*)(Bs + r * 64 + ((s ^ (r & 7)) * 8));
                }
                #pragma unroll
                for (int mf = 0; mf < 2; ++mf)
                    #pragma unroll
                    for (int nf = 0; nf < 4; ++nf)
                        acc[mf][nf] = __builtin_amdgcn_mfma_f32_16x16x32_bf16(
                            afr[ks][kh][mf], bfr[nf], acc[mf][nf], 0, 0, 0);
            }
        }
        // epilogue for this z
        const float* bias = (z == 0) ? conv_b : vp_b + (size_t)(z - 1) * CCH;
        short* vz = vb16 + (size_t)(z - 1) * MM * CCH;
        #pragma unroll
        for (int mf = 0; mf < 2; ++mf) {
            #pragma unroll
            for (int nf = 0; nf < 4; ++nf) {
                int col = n0 + wc * 64 + nf * 16 + l16;
                float bv = bias[col];
                #pragma unroll
                for (int j = 0; j < 4; ++j) {
                    int row = m0 + wr * 32 + mf * 16 + g * 4 + j;
                    float vv = acc[mf][nf][j] + bv;
                    if (z == 0) {
                        int p = row & (HWW - 1);
                        qb[(size_t)row * CCH + col] =
                            f2b(vv + b2f(pe_b[(size_t)p * CCH + col]));
                    } else {
                        int b = row >> 14, p = row & (HWW - 1);
                        int h = col >> 5, d = col & 31;
                        vz[(((size_t)(b * NHH + h)) * HWW + p) * DDIM + d] = f2b(vv);
                    }
                }
            }
        }
    }
}

// ---------- scores = q @ [off|aw] + bias  (N = 96, f32 out), BM=64 dbuf ----------
__global__ __launch_bounds__(256) void gemm_scores(
    const short* __restrict__ qb, const short* __restrict__ wt,
    const float* __restrict__ bias, float* __restrict__ scores)
{
    __shared__ short As[2 * 64 * 64];
    __shared__ short Bs[2 * 96 * 64];
    int tid = threadIdx.x;
    int m0 = blockIdx.y * 64;
    f32x4 acc[2][3] = {};
    gemm_core_db<64, 96, 32, 48>(qb, wt, As, Bs, m0, 0, tid, acc);

    int w = tid >> 6, lane = tid & 63;
    int g = lane >> 4, l16 = lane & 15;
    int wr = w >> 1, wc = w & 1;
    #pragma unroll
    for (int mf = 0; mf < 2; ++mf) {
        #pragma unroll
        for (int nf = 0; nf < 3; ++nf) {
            int col = wc * 48 + nf * 16 + l16;
            float bv = bias[col];
            #pragma unroll
            for (int j = 0; j < 4; ++j) {
                int row = m0 + wr * 32 + mf * 16 + g * 4 + j;
                scores[(size_t)row * 96 + col] = acc[mf][nf][j] + bv;
            }
        }
    }
}

// ---------- out = attn @ op_w + op_b + q(bf16), XCD-chunked flat grid (512) ----------
template<bool FINAL>
__global__ __launch_bounds__(256) void gemm_op(
    const short* __restrict__ attnb, const short* __restrict__ wt,
    const float* __restrict__ bias, const short* __restrict__ pe_b,
    float* __restrict__ outf, short* __restrict__ qb)
{
    __shared__ short As[2 * 128 * 64];
    __shared__ short Bs[2 * 128 * 64];
    int tid = threadIdx.x;
    int flat = blockIdx.x;
    int xcd = flat & 7;
    int idx = flat >> 3;            // 0..63 per XCD
    int mloc = idx & 31;
    int n0 = (idx >> 5) * 128;
    int m0 = (xcd * 32 + mloc) * 128;
    f32x4 acc[4][4] = {};
    gemm_core_db<128, 128, 64, 64>(attnb, wt, As, Bs, m0, n0, tid, acc);

    int w = tid >> 6, lane = tid & 63;
    int g = lane >> 4, l16 = lane & 15;
    int wr = w >> 1, wc = w & 1;
    #pragma unroll
    for (int mf = 0; mf < 4; ++mf) {
        #pragma unroll
        for (int nf = 0; nf < 4; ++nf) {
            int col = n0 + wc * 64 + nf * 16 + l16;
            float bv = bias[col];
            #pragma unroll
            for (int j = 0; j < 4; ++j) {
                int row = m0 + wr * 64 + mf * 16 + g * 4 + j;
                float vv = acc[mf][nf][j] + bv + b2f(qb[(size_t)row * CCH + col]);
                if (FINAL) {
                    outf[(size_t)row * CCH + col] = vv;
                } else {
                    int p = row & (HWW - 1);
                    qb[(size_t)row * CCH + col] =
                        f2b(vv + b2f(pe_b[(size_t)p * CCH + col]));
                }
            }
        }
    }
}

// ---------- deformable sampling + inline softmax (R10-proven 4 lanes/head) ----------
// v head-major [b][h][HW][32]: a point's 4 corners = 2 contiguous 128B segments.
__device__ __forceinline__ void fma8(uint4 u, float w, float* a) {
    a[0] = fmaf(__uint_as_float(u.x << 16), w, a[0]);
    a[1] = fmaf(__uint_as_float(u.x & 0xffff0000u), w, a[1]);
    a[2] = fmaf(__uint_as_float(u.y << 16), w, a[2]);
    a[3] = fmaf(__uint_as_float(u.y & 0xffff0000u), w, a[3]);
    a[4] = fmaf(__uint_as_float(u.z << 16), w, a[4]);
    a[5] = fmaf(__uint_as_float(u.z & 0xffff0000u), w, a[5]);
    a[6] = fmaf(__uint_as_float(u.w << 16), w, a[6]);
    a[7] = fmaf(__uint_as_float(u.w & 0xffff0000u), w, a[7]);
}

__global__ __launch_bounds__(256) void deform_kernel(
    const short* __restrict__ vb16, const float* __restrict__ scores,
    short* __restrict__ attnb)
{
    int tid = threadIdx.x;
    int gi = tid >> 2;
    int dl = (tid & 3) * 8;
    long gid = (long)blockIdx.x * 64 + gi; // (b*HW+p)*NH + h
    int h = (int)(gid & 7);
    long bp = gid >> 3;
    int p = (int)(bp & (HWW - 1));
    int b = (int)(bp >> 14);
    int y = p >> 7, x = p & 127;
    const float* srow = scores + bp * 96;
    float4 sc4 = *(const float4*)(srow + 64 + h * 4);
    float mx = fmaxf(fmaxf(sc4.x, sc4.y), fmaxf(sc4.z, sc4.w));
    float e0 = __expf(sc4.x - mx), e1 = __expf(sc4.y - mx);
    float e2 = __expf(sc4.z - mx), e3 = __expf(sc4.w - mx);
    float inv = 1.f / (e0 + e1 + e2 + e3);
    float wa4[4] = {e0 * inv, e1 * inv, e2 * inv, e3 * inv};
    float4 o01 = *(const float4*)(srow + h * 8);
    float4 o23 = *(const float4*)(srow + h * 8 + 4);
    float oxs[4] = {o01.x, o01.z, o23.x, o23.z};
    float oys[4] = {o01.y, o01.w, o23.y, o23.w};
    const short* vbase = vb16 + ((size_t)(b * NHH + h) * HWW) * DDIM + dl;
    float a[8] = {};
    #pragma unroll
    for (int pt = 0; pt < NPP; ++pt) {
        float wa = wa4[pt];
        float ix = (float)x + oxs[pt];     // grid_sample chain collapses to x+ox
        float iy = (float)y + oys[pt];
        float x0f = floorf(ix), y0f = floorf(iy);
        float fx = ix - x0f, fy = iy - y0f;
        // fold per-axis zero-padding validity into the weights (branchless)
        float wx0 = (x0f >= 0.f && x0f <= 127.f) ? (1.f - fx) : 0.f;
        float wx1 = (x0f >= -1.f && x0f <= 126.f) ? fx : 0.f;
        float wy0 = ((y0f >= 0.f && y0f <= 127.f) ? (1.f - fy) : 0.f) * wa;
        float wy1 = ((y0f >= -1.f && y0f <= 126.f) ? fy : 0.f) * wa;
        int xi0 = (int)fminf(fmaxf(x0f, 0.f), 127.f);
        int yi0 = (int)fminf(fmaxf(y0f, 0.f), 127.f);
        int xi1 = (int)fminf(fmaxf(x0f + 1.f, 0.f), 127.f);
        int yi1 = (int)fminf(fmaxf(y0f + 1.f, 0.f), 127.f);
        int r0 = yi0 << 7, r1 = yi1 << 7;
        uint4 u00 = *(const uint4*)(vbase + (size_t)(r0 + xi0) * DDIM);
        uint4 u01 = *(const uint4*)(vbase + (size_t)(r0 + xi1) * DDIM);
        uint4 u10 = *(const uint4*)(vbase + (size_t)(r1 + xi0) * DDIM);
        uint4 u11 = *(const uint4*)(vbase + (size_t)(r1 + xi1) * DDIM);
        fma8(u00, wx0 * wy0, a);
        fma8(u01, wx1 * wy0, a);
        fma8(u10, wx0 * wy1, a);
        fma8(u11, wx1 * wy1, a);
    }
    s16x8 o;
    #pragma unroll
    for (int j = 0; j < 8; ++j) o[j] = f2b(a[j]);
    *(s16x8*)&attnb[bp * CCH + h * DDIM + dl] = o;
}

extern "C" void kernel_launch(void* const* d_in, const int* in_sizes, int n_in,
                              void* d_out, int out_size, void* d_ws, size_t ws_size,
                              hipStream_t stream) {
    const float* ego       = (const float*)d_in[0];
    const float* conv_w    = (const float*)d_in[1];
    const float* conv_b    = (const float*)d_in[2];
    const float* in_scale  = (const float*)d_in[3];
    const float* out_scale = (const float*)d_in[4];
    const float* off_w     = (const float*)d_in[5];
    const float* off_b     = (const float*)d_in[6];
    const float* aw_w      = (const float*)d_in[7];
    const float* aw_b      = (const float*)d_in[8];
    const float* vp_w      = (const float*)d_in[9];
    const float* vp_b      = (const float*)d_in[10];
    const float* op_w      = (const float*)d_in[11];
    const float* op_b      = (const float*)d_in[12];
    float* out = (float*)d_out;

    float* scores   = (float*)d_ws;                    // MM*96 f32
    float* bias_cat = scores + (size_t)MM * 96;        // 4*96
    short* pe_b     = (short*)(bias_cat + 4 * 96);     // HWW*256 bf16
    short* ktb      = pe_b + (size_t)HWW * CCH;        // MM*256 bf16
    short* qb       = ktb + (size_t)MM * CCH;          // MM*256 bf16 (q + residual)
    short* vb16     = qb + (size_t)MM * CCH;           // 4 * MM*256 bf16 (head-major)
    short* attnb    = vb16 + (size_t)4 * MM * CCH;
    short* wt_big   = attnb + (size_t)MM * CCH;        // 9*256*256 bf16
    short* wt_offaw = wt_big + (size_t)9 * KK * CCH;   // 4*96*256 bf16

    pe_table_kernel<<<HWW * 128 / 256, 256, 0, stream>>>(out_scale, pe_b);
    convert_big_w<<<dim3(8, 8, 9), dim3(32, 8), 0, stream>>>(conv_w, vp_w, op_w, wt_big);
    convert_offaw_w<<<dim3(8, 3, 4), dim3(32, 8), 0, stream>>>(
        off_w, aw_w, off_b, aw_b, wt_offaw, bias_cat);
    transpose_pe_kernel<<<dim3(8, 512, 2), dim3(32, 8), 0, stream>>>(ego, in_scale, ktb);

    // A-slab persistent + A-frags in regs + in-block z loop; XCD-chunked m
    gemm_conv_v<<<1024, 256, 0, stream>>>(
        ktb, wt_big, conv_b, vp_b, pe_b, qb, vb16);

    for (int l = 0; l < 4; ++l) {
        gemm_scores<<<dim3(1, 512), 256, 0, stream>>>(
            qb, wt_offaw + (size_t)l * 96 * KK, bias_cat + l * 96, scores);
        deform_kernel<<<MM * NHH / 64, 256, 0, stream>>>(
            vb16 + (size_t)l * MM * CCH, scores, attnb);
        if (l < 3) {
            gemm_op<false><<<512, 256, 0, stream>>>(
                attnb, wt_big + (size_t)(5 + l) * KK * CCH, op_b + l * CCH,
                pe_b, nullptr, qb);
        } else {
            gemm_op<true><<<512, 256, 0, stream>>>(
                attnb, wt_big + (size_t)(5 + l) * KK * CCH, op_b + l * CCH,
                pe_b, out, qb);
        }
    }
}